// Round 19
// baseline (1043.675 us; speedup 1.0000x reference)
//
#include <hip/hip_runtime.h>
#include <hip/hip_fp16.h>

#define NTOT (1u<<20)   // nodes total
#define ETOT (1u<<24)   // edges total
#define NG   256        // graphs
#define NPG  4096       // nodes per graph
#define EPG  65536      // edges per graph

// ---------------- workspace layout (in 4-byte words) ----------------
constexpr size_t W_OFF  = 0;                       // (NTOT+64) ints: CSR row offsets (global positions)
constexpr size_t W_DEG2 = W_OFF + NTOT + 64;       // NTOT float2: (indeg, outdeg)
constexpr size_t W_SRT  = W_DEG2 + 2*(size_t)NTOT; // ETOT ushorts = ETOT/2 words: sorted local src ids
constexpr size_t W_HA   = W_SRT + ETOT/2;          // NTOT*12 f32
constexpr size_t W_HB   = W_HA + (size_t)NTOT*12;  // NTOT*12 f32
constexpr size_t W_GSUM = W_HB + (size_t)NTOT*12;  // 256*4 f32
constexpr size_t W_PG   = W_GSUM + 1024;           // 256*256*4 f32 pregates
constexpr size_t W_W16  = W_PG + 262144;           // 131072 words: W_hh f16 pairs uint4[64][512]

// ---------------- per-graph counting sort (CSR by dst) + FUSED conv1 (r9-verified) ----------------
#define SORT_LDS_BYTES (16384 + 4096 + 131072)
__global__ __launch_bounds__(1024) void k_sort(const int* __restrict__ esrc,
                                               const int* __restrict__ edst,
                                               int* __restrict__ off,
                                               float2* __restrict__ deg2,
                                               unsigned short* __restrict__ srt,
                                               const float* __restrict__ g1w,
                                               const float* __restrict__ g1b,
                                               float* __restrict__ ha) {
  extern __shared__ char sm[];
  int* cur   = (int*)sm;                   // [4096]
  int* bscan = (int*)(sm + 16384);         // [1024]
  int* hd    = (int*)(sm + 20480);         // [4096]
  int* hs    = (int*)(sm + 20480 + 16384); // [4096]
  unsigned short* slds = (unsigned short*)(sm + 20480);  // [65536], reuses hd/hs space
  const int g = blockIdx.x;
  const int t = threadIdx.x;
  const int ebase = g * EPG;
  const int nbase = g * NPG;
  for (int i = t; i < NPG; i += 1024) { hd[i] = 0; hs[i] = 0; }
  __syncthreads();
  for (int e = t; e < EPG; e += 1024) {
    int s = esrc[ebase + e] - nbase;
    int d = edst[ebase + e] - nbase;
    atomicAdd(&hs[s], 1);
    atomicAdd(&hd[d], 1);
  }
  __syncthreads();
  int a0 = hd[t*4+0], a1 = hd[t*4+1], a2 = hd[t*4+2], a3 = hd[t*4+3];
  int csum = a0 + a1 + a2 + a3;
  bscan[t] = csum;
  __syncthreads();
  for (int o = 1; o < 1024; o <<= 1) {
    int v = (t >= o) ? bscan[t - o] : 0;
    __syncthreads();
    bscan[t] += v;
    __syncthreads();
  }
  int e0 = bscan[t] - csum;  // exclusive chunk offset
  cur[t*4+0] = e0;
  cur[t*4+1] = e0 + a0;
  cur[t*4+2] = e0 + a0 + a1;
  cur[t*4+3] = e0 + a0 + a1 + a2;
  __syncthreads();
  for (int i = t; i < NPG; i += 1024) {
    off[nbase + i] = ebase + cur[i];
    deg2[nbase + i] = make_float2((float)hd[i], (float)hs[i]);
  }
  if (g == NG - 1 && t == 0) off[NTOT] = (int)ETOT;
  __syncthreads();   // hd/hs fully consumed; region becomes slds
  for (int e = t; e < EPG; e += 1024) {
    int s = esrc[ebase + e] - nbase;
    int d = edst[ebase + e] - nbase;
    int p = atomicAdd(&cur[d], 1);
    slds[p] = (unsigned short)s;
  }
  __syncthreads();   // cur/bscan dead from here; slds final
  uint4* dstv = (uint4*)(srt + (size_t)ebase);
  const uint4* srcv = (const uint4*)slds;
  for (int i = t; i < 8192; i += 1024)
    dstv[i] = srcv[i];
  // ---- fused conv1 ----
  if (t < 36) ((float*)bscan)[t] = (t < 24) ? g1w[t] : g1b[t - 24];
  for (int i = t; i < NPG; i += 1024) {
    float2 d2 = deg2[nbase + i];              // own-block write, L2-hot
    cur[i] = (int)((unsigned)(int)d2.x | ((unsigned)(int)d2.y << 16));
  }
  __syncthreads();
  const float* wv = (const float*)bscan;
  for (int q = 0; q < 4; ++q) {
    const int nloc = q * 1024 + t;
    const int s0 = off[nbase + nloc] - ebase;
    const int s1 = (nloc == NPG - 1) ? EPG : (off[nbase + nloc + 1] - ebase);
    float acc0 = 0.f, acc1 = 0.f;
    for (int e = s0; e < s1; ++e) {
      unsigned pd = (unsigned)cur[(int)slds[e]];
      acc0 += (float)(pd & 0xFFFFu);
      acc1 += (float)(pd >> 16);
    }
    float o[12];
    #pragma unroll
    for (int j = 0; j < 12; j++)
      o[j] = fmaxf(wv[2*j] * acc0 + wv[2*j+1] * acc1 + wv[24 + j], 0.f);
    float4* wout = (float4*)(ha + (size_t)(nbase + nloc) * 12);
    wout[0] = make_float4(o[0], o[1], o[2],  o[3]);
    wout[1] = make_float4(o[4], o[5], o[6],  o[7]);
    wout[2] = make_float4(o[8], o[9], o[10], o[11]);
  }
}

// ---------------- graph conv (layers 2,3): r12-exact (4096 blocks, 1 node/thread) ----------------
template<int FIN, int FOUT, bool POOL>
__global__ __launch_bounds__(256) void k_conv(const int* __restrict__ off,
                                              const unsigned short* __restrict__ srt,
                                              const float* __restrict__ hin,
                                              const float* __restrict__ W,
                                              const float* __restrict__ Bv,
                                              float* __restrict__ hout,
                                              float* __restrict__ gsum) {
  __shared__ float wsm[FOUT*FIN + FOUT];
  __shared__ float4 red[POOL ? 256 : 1];
  const int b = blockIdx.x;
  const int t = threadIdx.x;
  const int xcd = b & 7, slot = b >> 3;
  const int part = slot & 15, gidx = slot >> 4;   // 16 parts/graph, 32 graphs/XCD
  const int g = xcd + 8 * gidx;
  for (int i = t; i < FOUT*FIN + FOUT; i += 256)
    wsm[i] = (i < FOUT*FIN) ? W[i] : Bv[i - FOUT*FIN];
  __syncthreads();
  const int nbase = g * NPG;
  const int n = nbase + part * 256 + t;
  const int e0 = off[n], e1 = off[n + 1];
  float acc[FIN];
  #pragma unroll
  for (int j = 0; j < FIN; j++) acc[j] = 0.f;
  #pragma unroll 2
  for (int e = e0; e < e1; e++) {
    const int s = nbase + (int)srt[e];
    const float4* r = (const float4*)(hin + (size_t)s * 12);
    float4 v0 = r[0], v1 = r[1], v2 = r[2];
    acc[0] += v0.x; acc[1] += v0.y; acc[2]  += v0.z; acc[3]  += v0.w;
    acc[4] += v1.x; acc[5] += v1.y; acc[6]  += v1.z; acc[7]  += v1.w;
    acc[8] += v2.x; acc[9] += v2.y; acc[10] += v2.z; acc[11] += v2.w;
  }
  float o[FOUT];
  #pragma unroll
  for (int j = 0; j < FOUT; j++) {
    float v = wsm[FOUT*FIN + j];
    #pragma unroll
    for (int kk = 0; kk < FIN; kk++) v += wsm[j*FIN + kk] * acc[kk];
    o[j] = fmaxf(v, 0.f);
  }
  if constexpr (!POOL) {
    float4* wout = (float4*)(hout + (size_t)n * 12);
    wout[0] = make_float4(o[0], o[1], o[2],  o[3]);
    wout[1] = make_float4(o[4], o[5], o[6],  o[7]);
    wout[2] = make_float4(o[8], o[9], o[10], o[11]);
  } else {
    red[t] = make_float4(o[0], o[1], o[2], o[3]);
    __syncthreads();
    for (int o2 = 128; o2 > 0; o2 >>= 1) {
      if (t < o2) {
        red[t].x += red[t + o2].x; red[t].y += red[t + o2].y;
        red[t].z += red[t + o2].z; red[t].w += red[t + o2].w;
      }
      __syncthreads();
    }
    if (t == 0) {
      atomicAdd(&gsum[g*4+0], red[0].x);
      atomicAdd(&gsum[g*4+1], red[0].y);
      atomicAdd(&gsum[g*4+2], red[0].z);
      atomicAdd(&gsum[g*4+3], red[0].w);
    }
  }
}

// ---------------- pregates with fused fc1+concat (r17-verified): block = (step, gate) ----------------
__global__ __launch_bounds__(256) void k_pregates(const float* __restrict__ x,
                                                  const float* __restrict__ fc1w,
                                                  const float* __restrict__ fc1b,
                                                  const float* __restrict__ gsum,
                                                  const float* __restrict__ Wih,
                                                  const float* __restrict__ bih,
                                                  const float* __restrict__ bhh,
                                                  float* __restrict__ pg4) {
  __shared__ float seqs[32];
  const int b = blockIdx.x;
  const int step = b >> 2;     // = graph index
  const int gate = b & 3;
  const int rt = threadIdx.x;
  if (rt < 28) {
    float acc = fc1b[rt];
    const float* fr = fc1w + rt * 64;
    const float* xr = x + step * 64;
    #pragma unroll
    for (int k = 0; k < 64; k++) acc += fr[k] * xr[k];
    seqs[rt] = fmaxf(acc, 0.f);
  } else if (rt < 32) {
    seqs[rt] = gsum[step * 4 + (rt - 28)] * (1.0f / 4096.0f);
  }
  __syncthreads();
  const int row = gate * 256 + rt;
  float acc = bih[row] + bhh[row];
  const float4* wr = (const float4*)(Wih + (size_t)row * 32);
  const float4* s4 = (const float4*)seqs;
  #pragma unroll
  for (int c = 0; c < 8; c++) {
    float4 w = wr[c];
    float4 sv = s4[c];
    acc += w.x * sv.x + w.y * sv.y + w.z * sv.z + w.w * sv.w;
  }
  pg4[((size_t)step * 256 + rt) * 4 + gate] = acc;
}

// ---------------- W_hh f32 -> f16 pairs, uint4[j=0..63][t=0..511] (r13-verified) ----------------
__global__ __launch_bounds__(256) void k_w16(const float* __restrict__ Whh,
                                             unsigned int* __restrict__ w16) {
  const int pid = blockIdx.x * 256 + threadIdx.x;   // [0, 131072) uints
  const int q = pid >> 2, c = pid & 3;
  const int j = q >> 9, t = q & 511;
  const int u = t & 255, hf = t >> 8;
  const int R = u + 256 * (j >> 4);
  const int jj = hf * 16 + (j & 15);
  const int cp = jj * 4 + c;
  float2 v = ((const float2*)Whh)[(size_t)R * 128 + cp];
  __half2 h = __floats2half2_rn(v.x, v.y);
  w16[pid] = *(unsigned int*)&h;
}

// ---------------- LSTM: SINGLE CU, 512 thr, ALL 64 weight quads named (0 LDS weight slots) ----------------
typedef _Float16 half2_t __attribute__((ext_vector_type(2)));

__device__ inline float dot2(unsigned int a, unsigned int b, float c) {
  return __builtin_amdgcn_fdot2(__builtin_bit_cast(half2_t, a),
                                __builtin_bit_cast(half2_t, b), c, false);
}

__device__ inline float fast_sig(float x) { return 1.f / (1.f + __expf(-x)); }
__device__ inline float fast_tanh(float x) {
  float xc = fminf(fmaxf(x, -30.f), 30.f);
  float e = __expf(2.f * xc);
  return (e - 1.f) / (e + 1.f);
}

// r19 change: zero LDS weight slots. r13 (12 LDS)=371us vs r16 (18 LDS)=388us
// => each LDS weight slot costs ~2.8us (LDS pipe is the binding resource; the
// L2-remat leg is fully overlapped). All 64 quads named: compiler keeps ~24 in
// the 128-VGPR budget and remats ~40 from L2 per step. LDS now only h + pex.
#define DOT4(acc, ww, hv) \
  acc = dot2(ww.x, hv.x, acc); acc = dot2(ww.y, hv.y, acc); \
  acc = dot2(ww.z, hv.z, acc); acc = dot2(ww.w, hv.w, acc);
#define J4(ix, wa, wb, wc, wd) { const uint4 hv = hb4[ix]; \
  DOT4(a0, wa, hv) DOT4(a1, wb, hv) DOT4(a2, wc, hv) DOT4(a3, wd, hv) }

__global__ void __launch_bounds__(512, 1)
k_lstm1(const uint4* __restrict__ w16q,
        const float* __restrict__ pg4,
        float* __restrict__ out) {
  __shared__ unsigned int hbc[2 * 128];     // 1 KB (h as f16 pairs, 2 parities)
  __shared__ float4 pex[512];               // 8 KB (partial exchange)
  const int t = threadIdx.x;
  const int hf = t >> 8;
  const uint4 v0  = w16q[ 0*512+t], v1  = w16q[ 1*512+t], v2  = w16q[ 2*512+t], v3  = w16q[ 3*512+t];
  const uint4 v4  = w16q[ 4*512+t], v5  = w16q[ 5*512+t], v6  = w16q[ 6*512+t], v7  = w16q[ 7*512+t];
  const uint4 v8  = w16q[ 8*512+t], v9  = w16q[ 9*512+t], v10 = w16q[10*512+t], v11 = w16q[11*512+t];
  const uint4 v12 = w16q[12*512+t], v13 = w16q[13*512+t], v14 = w16q[14*512+t], v15 = w16q[15*512+t];
  const uint4 v16 = w16q[16*512+t], v17 = w16q[17*512+t], v18 = w16q[18*512+t], v19 = w16q[19*512+t];
  const uint4 v20 = w16q[20*512+t], v21 = w16q[21*512+t], v22 = w16q[22*512+t], v23 = w16q[23*512+t];
  const uint4 v24 = w16q[24*512+t], v25 = w16q[25*512+t], v26 = w16q[26*512+t], v27 = w16q[27*512+t];
  const uint4 v28 = w16q[28*512+t], v29 = w16q[29*512+t], v30 = w16q[30*512+t], v31 = w16q[31*512+t];
  const uint4 v32 = w16q[32*512+t], v33 = w16q[33*512+t], v34 = w16q[34*512+t], v35 = w16q[35*512+t];
  const uint4 v36 = w16q[36*512+t], v37 = w16q[37*512+t], v38 = w16q[38*512+t], v39 = w16q[39*512+t];
  const uint4 v40 = w16q[40*512+t], v41 = w16q[41*512+t], v42 = w16q[42*512+t], v43 = w16q[43*512+t];
  const uint4 v44 = w16q[44*512+t], v45 = w16q[45*512+t], v46 = w16q[46*512+t], v47 = w16q[47*512+t];
  const uint4 v48 = w16q[48*512+t], v49 = w16q[49*512+t], v50 = w16q[50*512+t], v51 = w16q[51*512+t];
  const uint4 v52 = w16q[52*512+t], v53 = w16q[53*512+t], v54 = w16q[54*512+t], v55 = w16q[55*512+t];
  const uint4 v56 = w16q[56*512+t], v57 = w16q[57*512+t], v58 = w16q[58*512+t], v59 = w16q[59*512+t];
  const uint4 v60 = w16q[60*512+t], v61 = w16q[61*512+t], v62 = w16q[62*512+t], v63 = w16q[63*512+t];
  if (t < 128) hbc[t] = 0u;    // h0 = 0
  float cs = 0.f;
  __syncthreads();
  for (int step = 0; step < 256; ++step) {
    const int par = step & 1;
    float4 pf;
    if (t < 256) pf = *(const float4*)(pg4 + ((size_t)step * 256 + t) * 4);
    const uint4* hb4 = (const uint4*)hbc + par * 32 + hf * 16;
    float a0 = 0.f, a1 = 0.f, a2 = 0.f, a3 = 0.f;
    J4( 0, v0,  v16, v32, v48)
    J4( 1, v1,  v17, v33, v49)
    J4( 2, v2,  v18, v34, v50)
    J4( 3, v3,  v19, v35, v51)
    J4( 4, v4,  v20, v36, v52)
    J4( 5, v5,  v21, v37, v53)
    J4( 6, v6,  v22, v38, v54)
    J4( 7, v7,  v23, v39, v55)
    J4( 8, v8,  v24, v40, v56)
    J4( 9, v9,  v25, v41, v57)
    J4(10, v10, v26, v42, v58)
    J4(11, v11, v27, v43, v59)
    J4(12, v12, v28, v44, v60)
    J4(13, v13, v29, v45, v61)
    J4(14, v14, v30, v46, v62)
    J4(15, v15, v31, v47, v63)
    pex[t] = make_float4(a0, a1, a2, a3);
    __syncthreads();
    if (t < 256) {
      float4 q = pex[t + 256];
      float gi = a0 + q.x + pf.x;
      float gf = a1 + q.y + pf.y;
      float gg = a2 + q.z + pf.z;
      float go = a3 + q.w + pf.w;
      float si = fast_sig(gi);
      float sf = fast_sig(gf);
      float so = fast_sig(go);
      float tg = fast_tanh(gg);
      cs = sf * cs + si * tg;
      float hn = so * fast_tanh(cs);
      out[step * 256 + t] = hn;
      ((unsigned short*)hbc)[((step + 1) & 1) * 256 + t] =
          __half_as_ushort(__float2half(hn));
    }
    __syncthreads();
  }
}

extern "C" void kernel_launch(void* const* d_in, const int* in_sizes, int n_in,
                              void* d_out, int out_size, void* d_ws, size_t ws_size,
                              hipStream_t stream) {
  const float* x    = (const float*)d_in[0];
  const int*   esrc = (const int*)d_in[1];
  const int*   edst = (const int*)d_in[2];
  // d_in[3] node_graph_ids: implied by node index (n >> 12)
  const float* fc1w = (const float*)d_in[4];
  const float* fc1b = (const float*)d_in[5];
  const float* g1w  = (const float*)d_in[6];
  const float* g1b  = (const float*)d_in[7];
  const float* g2w  = (const float*)d_in[8];
  const float* g2b  = (const float*)d_in[9];
  const float* g3w  = (const float*)d_in[10];
  const float* g3b  = (const float*)d_in[11];
  const float* Wih  = (const float*)d_in[12];
  const float* Whh  = (const float*)d_in[13];
  const float* bih  = (const float*)d_in[14];
  const float* bhh  = (const float*)d_in[15];
  // d_in[16], d_in[17]: w_omega/u_omega — result discarded by reference

  float* ws = (float*)d_ws;
  int*            off  = (int*)(ws + W_OFF);
  float*          deg2 = ws + W_DEG2;
  unsigned short* srt  = (unsigned short*)(ws + W_SRT);
  float*          ha   = ws + W_HA;
  float*          hb   = ws + W_HB;
  float*          gsum = ws + W_GSUM;
  float*          pg4  = ws + W_PG;
  unsigned int*   w16  = (unsigned int*)(ws + W_W16);

  hipMemsetAsync(gsum, 0, 1024 * 4, stream);
  k_sort<<<256, 1024, SORT_LDS_BYTES, stream>>>(esrc, edst, off, (float2*)deg2, srt,
                                                g1w, g1b, ha);
  k_w16<<<512, 256, 0, stream>>>(Whh, w16);
  k_conv<12, 12, false><<<4096, 256, 0, stream>>>(off, srt, ha, g2w, g2b, hb, nullptr);
  k_conv<12, 4, true ><<<4096, 256, 0, stream>>>(off, srt, hb, g3w, g3b, nullptr, gsum);
  k_pregates<<<1024, 256, 0, stream>>>(x, fc1w, fc1b, gsum, Wih, bih, bhh, pg4);
  k_lstm1<<<1, 512, 0, stream>>>((const uint4*)w16, pg4, (float*)d_out);
}

// Round 20
// 696.551 us; speedup vs baseline: 1.4983x; 1.4983x over previous
//
#include <hip/hip_runtime.h>
#include <hip/hip_fp16.h>

#define NTOT (1u<<20)   // nodes total
#define ETOT (1u<<24)   // edges total
#define NG   256        // graphs
#define NPG  4096       // nodes per graph
#define EPG  65536      // edges per graph

// ---------------- workspace layout (in 4-byte words) ----------------
constexpr size_t W_OFF  = 0;                       // (NTOT+64) ints: CSR row offsets (global positions)
constexpr size_t W_DEG2 = W_OFF + NTOT + 64;       // NTOT float2: (indeg, outdeg)
constexpr size_t W_SRT  = W_DEG2 + 2*(size_t)NTOT; // ETOT ushorts = ETOT/2 words: sorted local src ids
constexpr size_t W_HA   = W_SRT + ETOT/2;          // NTOT*12 f32
constexpr size_t W_HB   = W_HA + (size_t)NTOT*12;  // NTOT*12 f32
constexpr size_t W_GSUM = W_HB + (size_t)NTOT*12;  // 256*4 f32
constexpr size_t W_PG   = W_GSUM + 1024;           // 256*256*4 f32 pregates
constexpr size_t W_W16  = W_PG + 262144;           // 131072 words: W_hh f16 pairs uint4[64][512]

// ---------------- per-graph counting sort (CSR by dst) + FUSED conv1 (r9-verified) ----------------
#define SORT_LDS_BYTES (16384 + 4096 + 131072)
__global__ __launch_bounds__(1024) void k_sort(const int* __restrict__ esrc,
                                               const int* __restrict__ edst,
                                               int* __restrict__ off,
                                               float2* __restrict__ deg2,
                                               unsigned short* __restrict__ srt,
                                               const float* __restrict__ g1w,
                                               const float* __restrict__ g1b,
                                               float* __restrict__ ha) {
  extern __shared__ char sm[];
  int* cur   = (int*)sm;                   // [4096]
  int* bscan = (int*)(sm + 16384);         // [1024]
  int* hd    = (int*)(sm + 20480);         // [4096]
  int* hs    = (int*)(sm + 20480 + 16384); // [4096]
  unsigned short* slds = (unsigned short*)(sm + 20480);  // [65536], reuses hd/hs space
  const int g = blockIdx.x;
  const int t = threadIdx.x;
  const int ebase = g * EPG;
  const int nbase = g * NPG;
  for (int i = t; i < NPG; i += 1024) { hd[i] = 0; hs[i] = 0; }
  __syncthreads();
  for (int e = t; e < EPG; e += 1024) {
    int s = esrc[ebase + e] - nbase;
    int d = edst[ebase + e] - nbase;
    atomicAdd(&hs[s], 1);
    atomicAdd(&hd[d], 1);
  }
  __syncthreads();
  int a0 = hd[t*4+0], a1 = hd[t*4+1], a2 = hd[t*4+2], a3 = hd[t*4+3];
  int csum = a0 + a1 + a2 + a3;
  bscan[t] = csum;
  __syncthreads();
  for (int o = 1; o < 1024; o <<= 1) {
    int v = (t >= o) ? bscan[t - o] : 0;
    __syncthreads();
    bscan[t] += v;
    __syncthreads();
  }
  int e0 = bscan[t] - csum;  // exclusive chunk offset
  cur[t*4+0] = e0;
  cur[t*4+1] = e0 + a0;
  cur[t*4+2] = e0 + a0 + a1;
  cur[t*4+3] = e0 + a0 + a1 + a2;
  __syncthreads();
  for (int i = t; i < NPG; i += 1024) {
    off[nbase + i] = ebase + cur[i];
    deg2[nbase + i] = make_float2((float)hd[i], (float)hs[i]);
  }
  if (g == NG - 1 && t == 0) off[NTOT] = (int)ETOT;
  __syncthreads();   // hd/hs fully consumed; region becomes slds
  for (int e = t; e < EPG; e += 1024) {
    int s = esrc[ebase + e] - nbase;
    int d = edst[ebase + e] - nbase;
    int p = atomicAdd(&cur[d], 1);
    slds[p] = (unsigned short)s;
  }
  __syncthreads();   // cur/bscan dead from here; slds final
  uint4* dstv = (uint4*)(srt + (size_t)ebase);
  const uint4* srcv = (const uint4*)slds;
  for (int i = t; i < 8192; i += 1024)
    dstv[i] = srcv[i];
  // ---- fused conv1 ----
  if (t < 36) ((float*)bscan)[t] = (t < 24) ? g1w[t] : g1b[t - 24];
  for (int i = t; i < NPG; i += 1024) {
    float2 d2 = deg2[nbase + i];              // own-block write, L2-hot
    cur[i] = (int)((unsigned)(int)d2.x | ((unsigned)(int)d2.y << 16));
  }
  __syncthreads();
  const float* wv = (const float*)bscan;
  for (int q = 0; q < 4; ++q) {
    const int nloc = q * 1024 + t;
    const int s0 = off[nbase + nloc] - ebase;
    const int s1 = (nloc == NPG - 1) ? EPG : (off[nbase + nloc + 1] - ebase);
    float acc0 = 0.f, acc1 = 0.f;
    for (int e = s0; e < s1; ++e) {
      unsigned pd = (unsigned)cur[(int)slds[e]];
      acc0 += (float)(pd & 0xFFFFu);
      acc1 += (float)(pd >> 16);
    }
    float o[12];
    #pragma unroll
    for (int j = 0; j < 12; j++)
      o[j] = fmaxf(wv[2*j] * acc0 + wv[2*j+1] * acc1 + wv[24 + j], 0.f);
    float4* wout = (float4*)(ha + (size_t)(nbase + nloc) * 12);
    wout[0] = make_float4(o[0], o[1], o[2],  o[3]);
    wout[1] = make_float4(o[4], o[5], o[6],  o[7]);
    wout[2] = make_float4(o[8], o[9], o[10], o[11]);
  }
}

// ---------------- graph conv (layers 2,3): r12-exact (4096 blocks, 1 node/thread) ----------------
template<int FIN, int FOUT, bool POOL>
__global__ __launch_bounds__(256) void k_conv(const int* __restrict__ off,
                                              const unsigned short* __restrict__ srt,
                                              const float* __restrict__ hin,
                                              const float* __restrict__ W,
                                              const float* __restrict__ Bv,
                                              float* __restrict__ hout,
                                              float* __restrict__ gsum) {
  __shared__ float wsm[FOUT*FIN + FOUT];
  __shared__ float4 red[POOL ? 256 : 1];
  const int b = blockIdx.x;
  const int t = threadIdx.x;
  const int xcd = b & 7, slot = b >> 3;
  const int part = slot & 15, gidx = slot >> 4;   // 16 parts/graph, 32 graphs/XCD
  const int g = xcd + 8 * gidx;
  for (int i = t; i < FOUT*FIN + FOUT; i += 256)
    wsm[i] = (i < FOUT*FIN) ? W[i] : Bv[i - FOUT*FIN];
  __syncthreads();
  const int nbase = g * NPG;
  const int n = nbase + part * 256 + t;
  const int e0 = off[n], e1 = off[n + 1];
  float acc[FIN];
  #pragma unroll
  for (int j = 0; j < FIN; j++) acc[j] = 0.f;
  #pragma unroll 2
  for (int e = e0; e < e1; e++) {
    const int s = nbase + (int)srt[e];
    const float4* r = (const float4*)(hin + (size_t)s * 12);
    float4 v0 = r[0], v1 = r[1], v2 = r[2];
    acc[0] += v0.x; acc[1] += v0.y; acc[2]  += v0.z; acc[3]  += v0.w;
    acc[4] += v1.x; acc[5] += v1.y; acc[6]  += v1.z; acc[7]  += v1.w;
    acc[8] += v2.x; acc[9] += v2.y; acc[10] += v2.z; acc[11] += v2.w;
  }
  float o[FOUT];
  #pragma unroll
  for (int j = 0; j < FOUT; j++) {
    float v = wsm[FOUT*FIN + j];
    #pragma unroll
    for (int kk = 0; kk < FIN; kk++) v += wsm[j*FIN + kk] * acc[kk];
    o[j] = fmaxf(v, 0.f);
  }
  if constexpr (!POOL) {
    float4* wout = (float4*)(hout + (size_t)n * 12);
    wout[0] = make_float4(o[0], o[1], o[2],  o[3]);
    wout[1] = make_float4(o[4], o[5], o[6],  o[7]);
    wout[2] = make_float4(o[8], o[9], o[10], o[11]);
  } else {
    red[t] = make_float4(o[0], o[1], o[2], o[3]);
    __syncthreads();
    for (int o2 = 128; o2 > 0; o2 >>= 1) {
      if (t < o2) {
        red[t].x += red[t + o2].x; red[t].y += red[t + o2].y;
        red[t].z += red[t + o2].z; red[t].w += red[t + o2].w;
      }
      __syncthreads();
    }
    if (t == 0) {
      atomicAdd(&gsum[g*4+0], red[0].x);
      atomicAdd(&gsum[g*4+1], red[0].y);
      atomicAdd(&gsum[g*4+2], red[0].z);
      atomicAdd(&gsum[g*4+3], red[0].w);
    }
  }
}

// ---------------- pregates with fused fc1+concat (r17/r18-verified): block = (step, gate) ----------------
__global__ __launch_bounds__(256) void k_pregates(const float* __restrict__ x,
                                                  const float* __restrict__ fc1w,
                                                  const float* __restrict__ fc1b,
                                                  const float* __restrict__ gsum,
                                                  const float* __restrict__ Wih,
                                                  const float* __restrict__ bih,
                                                  const float* __restrict__ bhh,
                                                  float* __restrict__ pg4) {
  __shared__ float seqs[32];
  const int b = blockIdx.x;
  const int step = b >> 2;     // = graph index
  const int gate = b & 3;
  const int rt = threadIdx.x;
  if (rt < 28) {
    float acc = fc1b[rt];
    const float* fr = fc1w + rt * 64;
    const float* xr = x + step * 64;
    #pragma unroll
    for (int k = 0; k < 64; k++) acc += fr[k] * xr[k];
    seqs[rt] = fmaxf(acc, 0.f);
  } else if (rt < 32) {
    seqs[rt] = gsum[step * 4 + (rt - 28)] * (1.0f / 4096.0f);
  }
  __syncthreads();
  const int row = gate * 256 + rt;
  float acc = bih[row] + bhh[row];
  const float4* wr = (const float4*)(Wih + (size_t)row * 32);
  const float4* s4 = (const float4*)seqs;
  #pragma unroll
  for (int c = 0; c < 8; c++) {
    float4 w = wr[c];
    float4 sv = s4[c];
    acc += w.x * sv.x + w.y * sv.y + w.z * sv.z + w.w * sv.w;
  }
  pg4[((size_t)step * 256 + rt) * 4 + gate] = acc;
}

// ---------------- W_hh f32 -> f16 pairs, uint4[j=0..63][t=0..511] (r13-verified) ----------------
__global__ __launch_bounds__(256) void k_w16(const float* __restrict__ Whh,
                                             unsigned int* __restrict__ w16) {
  const int pid = blockIdx.x * 256 + threadIdx.x;   // [0, 131072) uints
  const int q = pid >> 2, c = pid & 3;
  const int j = q >> 9, t = q & 511;
  const int u = t & 255, hf = t >> 8;
  const int R = u + 256 * (j >> 4);
  const int jj = hf * 16 + (j & 15);
  const int cp = jj * 4 + c;
  float2 v = ((const float2*)Whh)[(size_t)R * 128 + cp];
  __half2 h = __floats2half2_rn(v.x, v.y);
  w16[pid] = *(unsigned int*)&h;
}

// ---------------- LSTM: SINGLE CU, 512 thr, 52 named + 12 LDS slots (r13-exact, 371us) ----------------
typedef _Float16 half2_t __attribute__((ext_vector_type(2)));

__device__ inline float dot2(unsigned int a, unsigned int b, float c) {
  return __builtin_amdgcn_fdot2(__builtin_bit_cast(half2_t, a),
                                __builtin_bit_cast(half2_t, b), c, false);
}

__device__ inline float fast_sig(float x) { return 1.f / (1.f + __expf(-x)); }
__device__ inline float fast_tanh(float x) {
  float xc = fminf(fmaxf(x, -30.f), 30.f);
  float e = __expf(2.f * xc);
  return (e - 1.f) / (e + 1.f);
}

// Knob sweep conclusion (r13/r15/r16/r19): LDS weight slots 0/12/18 ->
// 719/371/388 us. 12 slots = pipe-balance optimum between the LDS pipe and
// the (overlapped) L2-remat leg under the toolchain's hard 128-VGPR grant.
#define DOT4(acc, ww, hv) \
  acc = dot2(ww.x, hv.x, acc); acc = dot2(ww.y, hv.y, acc); \
  acc = dot2(ww.z, hv.z, acc); acc = dot2(ww.w, hv.w, acc);
#define J4(ix, wa, wb, wc, wd) { const uint4 hv = hb4[ix]; \
  DOT4(a0, wa, hv) DOT4(a1, wb, hv) DOT4(a2, wc, hv) DOT4(a3, wd, hv) }
#define J3L(ix, wa, wb, wc, slot) { const uint4 hv = hb4[ix]; \
  const uint4 wl = wlds[(slot)*512 + t]; \
  DOT4(a0, wa, hv) DOT4(a1, wb, hv) DOT4(a2, wc, hv) DOT4(a3, wl, hv) }

__global__ void __launch_bounds__(512, 1)
k_lstm1(const uint4* __restrict__ w16q,
        const float* __restrict__ pg4,
        float* __restrict__ out) {
  __shared__ uint4 wlds[12 * 512];          // 96 KB
  __shared__ unsigned int hbc[2 * 128];     // 1 KB
  __shared__ float4 pex[512];               // 8 KB
  const int t = threadIdx.x;
  const int hf = t >> 8;
  const uint4 w0  = w16q[ 0*512+t], w1  = w16q[ 1*512+t], w2  = w16q[ 2*512+t], w3  = w16q[ 3*512+t];
  const uint4 w4  = w16q[ 4*512+t], w5  = w16q[ 5*512+t], w6  = w16q[ 6*512+t], w7  = w16q[ 7*512+t];
  const uint4 w8  = w16q[ 8*512+t], w9  = w16q[ 9*512+t], w10 = w16q[10*512+t], w11 = w16q[11*512+t];
  const uint4 w12 = w16q[12*512+t], w13 = w16q[13*512+t], w14 = w16q[14*512+t], w15 = w16q[15*512+t];
  const uint4 wA0 = w16q[16*512+t], w17 = w16q[17*512+t], w18 = w16q[18*512+t], w19 = w16q[19*512+t];
  const uint4 w20 = w16q[20*512+t], w21 = w16q[21*512+t], w22 = w16q[22*512+t], w23 = w16q[23*512+t];
  const uint4 w24 = w16q[24*512+t], w25 = w16q[25*512+t], w26 = w16q[26*512+t], w27 = w16q[27*512+t];
  const uint4 w28 = w16q[28*512+t], w29 = w16q[29*512+t], w30 = w16q[30*512+t], w31 = w16q[31*512+t];
  const uint4 w32 = w16q[32*512+t], w33 = w16q[33*512+t], w34 = w16q[34*512+t], w35 = w16q[35*512+t];
  const uint4 w36 = w16q[36*512+t], w37 = w16q[37*512+t], w38 = w16q[38*512+t], w39 = w16q[39*512+t];
  const uint4 w40 = w16q[40*512+t], w41 = w16q[41*512+t], w42 = w16q[42*512+t], w43 = w16q[43*512+t];
  const uint4 w44 = w16q[44*512+t], w45 = w16q[45*512+t], w46 = w16q[46*512+t], w47 = w16q[47*512+t];
  const uint4 w48 = w16q[48*512+t], w49 = w16q[49*512+t], w50 = w16q[50*512+t], w51 = w16q[51*512+t];
  #pragma unroll
  for (int k = 0; k < 12; k++) wlds[k*512 + t] = w16q[(52 + k)*512 + t];
  if (t < 128) hbc[t] = 0u;    // h0 = 0
  float cs = 0.f;
  __syncthreads();
  for (int step = 0; step < 256; ++step) {
    const int par = step & 1;
    float4 pf;
    if (t < 256) pf = *(const float4*)(pg4 + ((size_t)step * 256 + t) * 4);
    const uint4* hb4 = (const uint4*)hbc + par * 32 + hf * 16;
    float a0 = 0.f, a1 = 0.f, a2 = 0.f, a3 = 0.f;
    J4 ( 0, w0,  wA0, w32, w48)
    J4 ( 1, w1,  w17, w33, w49)
    J4 ( 2, w2,  w18, w34, w50)
    J4 ( 3, w3,  w19, w35, w51)
    J3L( 4, w4,  w20, w36, 0)
    J3L( 5, w5,  w21, w37, 1)
    J3L( 6, w6,  w22, w38, 2)
    J3L( 7, w7,  w23, w39, 3)
    J3L( 8, w8,  w24, w40, 4)
    J3L( 9, w9,  w25, w41, 5)
    J3L(10, w10, w26, w42, 6)
    J3L(11, w11, w27, w43, 7)
    J3L(12, w12, w28, w44, 8)
    J3L(13, w13, w29, w45, 9)
    J3L(14, w14, w30, w46, 10)
    J3L(15, w15, w31, w47, 11)
    pex[t] = make_float4(a0, a1, a2, a3);
    __syncthreads();
    if (t < 256) {
      float4 q = pex[t + 256];
      float gi = a0 + q.x + pf.x;
      float gf = a1 + q.y + pf.y;
      float gg = a2 + q.z + pf.z;
      float go = a3 + q.w + pf.w;
      float si = fast_sig(gi);
      float sf = fast_sig(gf);
      float so = fast_sig(go);
      float tg = fast_tanh(gg);
      cs = sf * cs + si * tg;
      float hn = so * fast_tanh(cs);
      out[step * 256 + t] = hn;
      ((unsigned short*)hbc)[((step + 1) & 1) * 256 + t] =
          __half_as_ushort(__float2half(hn));
    }
    __syncthreads();
  }
}

extern "C" void kernel_launch(void* const* d_in, const int* in_sizes, int n_in,
                              void* d_out, int out_size, void* d_ws, size_t ws_size,
                              hipStream_t stream) {
  const float* x    = (const float*)d_in[0];
  const int*   esrc = (const int*)d_in[1];
  const int*   edst = (const int*)d_in[2];
  // d_in[3] node_graph_ids: implied by node index (n >> 12)
  const float* fc1w = (const float*)d_in[4];
  const float* fc1b = (const float*)d_in[5];
  const float* g1w  = (const float*)d_in[6];
  const float* g1b  = (const float*)d_in[7];
  const float* g2w  = (const float*)d_in[8];
  const float* g2b  = (const float*)d_in[9];
  const float* g3w  = (const float*)d_in[10];
  const float* g3b  = (const float*)d_in[11];
  const float* Wih  = (const float*)d_in[12];
  const float* Whh  = (const float*)d_in[13];
  const float* bih  = (const float*)d_in[14];
  const float* bhh  = (const float*)d_in[15];
  // d_in[16], d_in[17]: w_omega/u_omega — result discarded by reference

  float* ws = (float*)d_ws;
  int*            off  = (int*)(ws + W_OFF);
  float*          deg2 = ws + W_DEG2;
  unsigned short* srt  = (unsigned short*)(ws + W_SRT);
  float*          ha   = ws + W_HA;
  float*          hb   = ws + W_HB;
  float*          gsum = ws + W_GSUM;
  float*          pg4  = ws + W_PG;
  unsigned int*   w16  = (unsigned int*)(ws + W_W16);

  hipMemsetAsync(gsum, 0, 1024 * 4, stream);
  k_sort<<<256, 1024, SORT_LDS_BYTES, stream>>>(esrc, edst, off, (float2*)deg2, srt,
                                                g1w, g1b, ha);
  k_w16<<<512, 256, 0, stream>>>(Whh, w16);
  k_conv<12, 12, false><<<4096, 256, 0, stream>>>(off, srt, ha, g2w, g2b, hb, nullptr);
  k_conv<12, 4, true ><<<4096, 256, 0, stream>>>(off, srt, hb, g3w, g3b, nullptr, gsum);
  k_pregates<<<1024, 256, 0, stream>>>(x, fc1w, fc1b, gsum, Wih, bih, bhh, pg4);
  k_lstm1<<<1, 512, 0, stream>>>((const uint4*)w16, pg4, (float*)d_out);
}